// Round 9
// baseline (8277.271 us; speedup 1.0000x reference)
//
#include <hip/hip_runtime.h>
#include <hip/hip_bf16.h>

// BiLSTM classifier, MI355X — round 9: fix the VGPR clamp.
// Evidence r4/r6/r8: hipcc's __launch_bounds__ 2nd arg behaves as CUDA-style
// MIN BLOCKS PER CU (r4 (512,2)->128 VGPR, r8 (1024,4)->clamped->64 VGPR).
// (1024,1) -> 1 block/CU = 4 waves/SIMD -> 128-VGPR budget; live set ~112.
// Otherwise identical to round 8: probe -> prep -> embed -> rnn (L2-streamed
// weight B-frags through 12-slot rotating reg buffer) -> head.

typedef __attribute__((ext_vector_type(8))) short bf16x8;
typedef __attribute__((ext_vector_type(4))) float f32x4;

#define S_LEN 512

// ws layout (bytes)
#define XF_OFF   0ULL
#define XF_SZ    (512ULL*16*4*64*16)           // 33,554,432
#define WF_OFF   (XF_OFF + XF_SZ)
#define WF_SZ    (2ULL*16*48*64*16)            // 1,572,864
#define FEAT_OFF (WF_OFF + WF_SZ)
#define FEAT_SZ  (256ULL*512*4)                // 524,288
#define FLAG_OFF (FEAT_OFF + FEAT_SZ)
#define WS_NEED  (FLAG_OFF + 16)

__device__ __forceinline__ short f2bf(float f){
  union { float f; unsigned u; } v; v.f = f;
  unsigned u = v.u;
  u += 0x7fffu + ((u >> 16) & 1u);   // RNE
  return (short)(u >> 16);
}
__device__ __forceinline__ float fsig(float x){
  float t = __builtin_amdgcn_exp2f(-1.44269504f * x);
  return __builtin_amdgcn_rcpf(1.0f + t);
}
__device__ __forceinline__ float ftanh(float x){
  float t = __builtin_amdgcn_exp2f(2.88539008f * x);   // e^{2x}
  return 1.0f - 2.0f * __builtin_amdgcn_rcpf(1.0f + t);
}
__device__ __forceinline__ int pack2(float a, float b){
  return (int)(unsigned short)f2bf(a) | ((int)(unsigned short)f2bf(b) << 16);
}
// k-offset within a K=32 chunk for input-fragment element j, lane-half h=(lane>>4).
// flag=1: contiguous (k = 8h+j). flag=0: split halves (k = 4h+j | 16+4h+(j-4)).
__device__ __forceinline__ int koff(int flag, int h, int j){
  return flag ? (8*h + j) : (j < 4 ? 4*h + j : 16 + 4*h + (j-4));
}
// Assemble an A-fragment (8 bf16) from a row of 16-bit LDS at colbase.
__device__ __forceinline__ bf16x8 loadA(const short* p, int colbase, int h, int flag){
  if (flag){
    return *(const bf16x8*)(p + colbase + 8*h);
  } else {
    short4 lo = *(const short4*)(p + colbase + 4*h);
    short4 hi = *(const short4*)(p + colbase + 16 + 4*h);
    bf16x8 r;
    r[0]=lo.x; r[1]=lo.y; r[2]=lo.z; r[3]=lo.w;
    r[4]=hi.x; r[5]=hi.y; r[6]=hi.z; r[7]=hi.w;
    return r;
  }
}

// ---------------- probe: decide MFMA input-fragment layout ------------------
__device__ __noinline__ void spin_units(int n){
  float x = 1.5f;
  for (int i=0; i<n*300; i++) x = __builtin_amdgcn_rcpf(x + 1.0f);
  asm volatile("" :: "v"(x));
}
__global__ __launch_bounds__(64) void probe_kernel(char* ws){
  int l = threadIdx.x;
  float dref[4]; int n = l & 15;
  #pragma unroll
  for (int r=0;r<4;r++){
    int m = 4*(l>>4) + r; float s = 0.f;
    for (int k=0;k<32;k++)
      s += (0.25f*(float)((m*7+k*3)%5-2)) * (0.125f*(float)((k*5+n*11)%7-3));
    dref[r] = s;
  }
  f32x4 zero = {0.f,0.f,0.f,0.f};
  int bad[2];
  #pragma unroll
  for (int cand=0; cand<2; cand++){          // 0=split, 1=contiguous
    bf16x8 a, b;
    #pragma unroll
    for (int j=0;j<8;j++){
      int k = koff(cand, l>>4, j);
      a[j] = f2bf(0.25f*(float)(((l&15)*7+k*3)%5-2));
      b[j] = f2bf(0.125f*(float)((k*5+(l&15)*11)%7-3));
    }
    f32x4 d = __builtin_amdgcn_mfma_f32_16x16x32_bf16(a,b,zero,0,0,0);
    int bb = 0;
    #pragma unroll
    for (int r=0;r<4;r++) bb |= (fabsf(d[r]-dref[r]) > 1e-4f) ? 1 : 0;
    bad[cand] = bb;
  }
  unsigned long long B2 = __ballot(bad[1]);
  unsigned long long B1 = __ballot(bad[0]);
  if (l == 0) *(int*)(ws + FLAG_OFF) = (B2 == 0ULL) ? 1 : 0;
  if (B2) spin_units(10);
  if (B1) spin_units(30);
}

// ---------------- prep: pack Wh,Wi -> per-wave streamed B-frags -------------
// WF[e], e = ((dir*16+ww)*48 + f)*64 + lane, f = cs*4+G; elem j:
//   cs<4: Wi[cs*32 + koff][n], cs>=4: Wh[(cs-4)*32 + koff][n]
//   n = G*256 + ww*16 + (lane&15)
__global__ __launch_bounds__(256) void prep_kernel(const float* Wh_f, const float* Wh_b,
    const float* Wi_f, const float* Wi_b, char* ws){
  const int flag = *(const int*)(ws + FLAG_OFF);
  int e = blockIdx.x*256 + threadIdx.x;     // 98304 total
  int lane = e&63;
  int q = e>>6;                              // (dir*16+ww)*48 + f
  int f = q % 48, dw = q / 48;
  int ww = dw & 15, dir = dw >> 4;
  int cs = f>>2, G = f&3;
  const float* W; int kb;
  if (cs < 4){ W = dir ? Wi_b : Wi_f; kb = cs*32; }
  else       { W = dir ? Wh_b : Wh_f; kb = (cs-4)*32; }
  int nn = G*256 + ww*16 + (lane&15);
  int h = lane>>4;
  int kj[8];
  #pragma unroll
  for (int j=0;j<8;j++) kj[j] = kb + koff(flag, h, j);
  int4 pv;
  pv.x = pack2(W[kj[0]*1024+nn], W[kj[1]*1024+nn]);
  pv.y = pack2(W[kj[2]*1024+nn], W[kj[3]*1024+nn]);
  pv.z = pack2(W[kj[4]*1024+nn], W[kj[5]*1024+nn]);
  pv.w = pack2(W[kj[6]*1024+nn], W[kj[7]*1024+nn]);
  ((int4*)(ws + WF_OFF))[e] = pv;
}

// ---------------- embed: x as A-fragments: XF[t][blk][ks][lane] 16B ---------
__global__ __launch_bounds__(256) void embed_kernel(const int* tokens, const float* emb,
    char* ws){
  const int flag = *(const int*)(ws + FLAG_OFF);
  int e = blockIdx.x;               // 8192 = t*16 + blk
  int t = e >> 4, blk = e & 15;
  int tid = threadIdx.x;
  int ks = tid >> 6, lane = tid & 63;
  int h = lane >> 4, m = lane & 15;
  int b = blk*16 + m;
  int tok = tokens[b*S_LEN + t];
  const float* er = emb + (size_t)tok*128 + ks*32;
  float4 v0, v1;
  if (flag){
    v0 = *(const float4*)(er + 8*h);
    v1 = *(const float4*)(er + 8*h + 4);
  } else {
    v0 = *(const float4*)(er + 4*h);
    v1 = *(const float4*)(er + 16 + 4*h);
  }
  int4 pv;
  pv.x = pack2(v0.x,v0.y); pv.y = pack2(v0.z,v0.w);
  pv.z = pack2(v1.x,v1.y); pv.w = pack2(v1.z,v1.w);
  ((int4*)(ws + XF_OFF))[((size_t)e*4 + ks)*64 + lane] = pv;
}

// ---------------- rnn: 32 blocks x 1024 thr, streamed weights ---------------
__device__ __forceinline__ void lstm_step(
    int t, int dir, int blk, int l, int flag, int hcol,
    const int4* xf4, const int4* wfw,
    int4 (&bq)[12], int4 (&xq)[4],
    const float (&bias)[4],
    const short* hRead, short* hWrite,
    float (&c)[4])
{
  const int hh = l>>4;
  const short* hR = hRead + (l&15)*264;
  f32x4 acc[4];
  #pragma unroll
  for (int G=0; G<4; G++){
    f32x4 v = {bias[G],bias[G],bias[G],bias[G]}; acc[G] = v;
  }
  // 2-deep LDS prefetch of h A-frags (chunks 4,5 first)
  bf16x8 afA = loadA(hR, 0,  hh, flag);
  bf16x8 afB = loadA(hR, 32, hh, flag);

  #pragma unroll
  for (int cs=0; cs<12; cs++){
    bf16x8 af;
    if (cs < 4)       af = __builtin_bit_cast(bf16x8, xq[cs]);
    else if (cs & 1){ af = afB; if (cs < 10) afB = loadA(hR, (cs-2)*32, hh, flag); }
    else            { af = afA; if (cs < 10) afA = loadA(hR, (cs-2)*32, hh, flag); }
    #pragma unroll
    for (int G=0; G<4; G++){
      const int f = cs*4 + G;
      acc[G] = __builtin_amdgcn_mfma_f32_16x16x32_bf16(af,
                 __builtin_bit_cast(bf16x8, bq[f%12]), acc[G], 0,0,0);
    }
    // refill slots with f+12 (mod 48): lead = 12 fragments, wraps across steps
    #pragma unroll
    for (int G=0; G<4; G++){
      const int f = cs*4 + G;
      bq[f%12] = wfw[(size_t)((f+12)%48)*64 + l];
    }
    if (cs == 3){
      // xq consumed; reload for t+1 (lands during chunks 4..11 + gates)
      int tn = (t+1 < S_LEN) ? t+1 : t;
      int tt = dir ? (S_LEN-1-tn) : tn;
      size_t xi = (((size_t)tt*16 + blk)*4)*64 + l;
      xq[0] = xf4[xi];     xq[1] = xf4[xi+64];
      xq[2] = xf4[xi+128]; xq[3] = xf4[xi+192];
    }
  }
  // gates (i,f,g,o = acc[0..3]); batch row m = 4*(l>>4)+r, hidden col hcol
  #pragma unroll
  for (int r=0; r<4; r++){
    float iv = acc[0][r];
    float fv = acc[1][r];
    float gv = acc[2][r];
    float ov = acc[3][r];
    float cc = fsig(fv)*c[r] + fsig(iv)*ftanh(gv);
    c[r] = cc;
    float hhv = fsig(ov)*ftanh(cc);
    hWrite[(4*(l>>4)+r)*264 + hcol] = f2bf(hhv);
  }
  __syncthreads();
}

__global__ __launch_bounds__(1024, 1) void rnn_kernel(const float* b_f, const float* b_b,
    char* ws){
  const int flag = *(const int*)(ws + FLAG_OFF);
  int bid = blockIdx.x; int dir = bid>>4, blk = bid&15;
  int tid = threadIdx.x; int ww = tid>>6, l = tid&63;
  __shared__ short hbuf[2][16*264];
  for (int i=tid; i<16*264; i+=1024) hbuf[0][i] = 0;
  const int4* xf4 = (const int4*)(ws + XF_OFF);
  const int4* wfw = (const int4*)(ws + WF_OFF) + ((size_t)(dir*16 + ww)*48)*64;
  float bias[4];
  {
    const float* bh = dir ? b_b : b_f;
    #pragma unroll
    for (int G=0; G<4; G++) bias[G] = bh[G*256 + ww*16 + (l&15)];
  }
  const int hcol = ww*16 + (l&15);
  float c[4] = {0,0,0,0};
  int4 bq[12], xq[4];
  #pragma unroll
  for (int s=0; s<12; s++) bq[s] = wfw[(size_t)s*64 + l];
  {
    int tt0 = dir ? (S_LEN-1) : 0;
    size_t xi0 = (((size_t)tt0*16 + blk)*4)*64 + l;
    xq[0]=xf4[xi0];     xq[1]=xf4[xi0+64];
    xq[2]=xf4[xi0+128]; xq[3]=xf4[xi0+192];
  }
  __syncthreads();
  #pragma unroll 1
  for (int t=0; t<S_LEN; t+=2){
    lstm_step(t,   dir, blk, l, flag, hcol, xf4, wfw, bq, xq, bias, hbuf[0], hbuf[1], c);
    lstm_step(t+1, dir, blk, l, flag, hcol, xf4, wfw, bq, xq, bias, hbuf[1], hbuf[0], c);
  }
  float* feat = (float*)(ws + FEAT_OFF);
  #pragma unroll
  for (int r=0; r<4; r++)
    feat[((size_t)blk*16 + 4*(l>>4)+r)*512 + dir*256 + hcol] = c[r];
}

// ---------------- head: feat@Wd+bd ------------------------------------------
__global__ __launch_bounds__(256) void head_kernel(const float* Wd, const float* bd,
    const char* ws, float* out){
  __shared__ float wds[4096];
  int tid = threadIdx.x;
  for (int i=tid; i<4096; i+=256) wds[i] = Wd[i];
  __syncthreads();
  if (tid < 128){
    int row = blockIdx.x*16 + (tid>>3), col = tid&7;
    const float* fr = (const float*)(ws + FEAT_OFF) + (size_t)row*512;
    float s = bd[col];
    #pragma unroll 8
    for (int k=0;k<512;k++) s += fr[k]*wds[k*8+col];
    out[row*8+col] = s;
  }
}

extern "C" void kernel_launch(void* const* d_in, const int* in_sizes, int n_in,
                              void* d_out, int out_size, void* d_ws, size_t ws_size,
                              hipStream_t stream) {
  const int*   tokens = (const int*)d_in[0];
  const float* emb    = (const float*)d_in[1];
  const float* Wi_f   = (const float*)d_in[2];
  const float* Wh_f   = (const float*)d_in[3];
  const float* b_f    = (const float*)d_in[4];
  const float* Wi_b   = (const float*)d_in[5];
  const float* Wh_b   = (const float*)d_in[6];
  const float* b_b    = (const float*)d_in[7];
  const float* Wd     = (const float*)d_in[8];
  const float* bd     = (const float*)d_in[9];
  char* ws = (char*)d_ws;
  float* out = (float*)d_out;

  if (ws_size < WS_NEED) return;   // fail cleanly instead of faulting

  hipLaunchKernelGGL(probe_kernel, dim3(1),    dim3(64),   0, stream, ws);
  hipLaunchKernelGGL(prep_kernel,  dim3(384),  dim3(256),  0, stream, Wh_f, Wh_b, Wi_f, Wi_b, ws);
  hipLaunchKernelGGL(embed_kernel, dim3(8192), dim3(256),  0, stream, tokens, emb, ws);
  hipLaunchKernelGGL(rnn_kernel,   dim3(32),   dim3(1024), 0, stream, b_f, b_b, ws);
  hipLaunchKernelGGL(head_kernel,  dim3(16),   dim3(256),  0, stream, Wd, bd, ws, out);
}

// Round 10
// 8253.199 us; speedup vs baseline: 1.0029x; 1.0029x over previous
//
#include <hip/hip_runtime.h>
#include <hip/hip_bf16.h>

// BiLSTM classifier, MI355X — round 10: force the VGPR budget via the
// backend-native attribute.
// Evidence r6/r8/r9: __launch_bounds__ 2nd arg is IGNORED (64 VGPR for
// (1024), (1024,4), (1024,1) alike; identical dur) -> allocator defaults
// 1024-thread kernels to 8 waves/EU = 64 VGPR, spilling the ~106-reg live
// set to scratch (the 38k cyc/step stall, MfmaUtil 1%).
// Fix: __attribute__((amdgpu_waves_per_eu(4,4))) -> 512/4 = 128 VGPR cap.
// Everything else identical to round 9 (single-knob experiment).

typedef __attribute__((ext_vector_type(8))) short bf16x8;
typedef __attribute__((ext_vector_type(4))) float f32x4;

#define S_LEN 512

// ws layout (bytes)
#define XF_OFF   0ULL
#define XF_SZ    (512ULL*16*4*64*16)           // 33,554,432
#define WF_OFF   (XF_OFF + XF_SZ)
#define WF_SZ    (2ULL*16*48*64*16)            // 1,572,864
#define FEAT_OFF (WF_OFF + WF_SZ)
#define FEAT_SZ  (256ULL*512*4)                // 524,288
#define FLAG_OFF (FEAT_OFF + FEAT_SZ)
#define WS_NEED  (FLAG_OFF + 16)

__device__ __forceinline__ short f2bf(float f){
  union { float f; unsigned u; } v; v.f = f;
  unsigned u = v.u;
  u += 0x7fffu + ((u >> 16) & 1u);   // RNE
  return (short)(u >> 16);
}
__device__ __forceinline__ float fsig(float x){
  float t = __builtin_amdgcn_exp2f(-1.44269504f * x);
  return __builtin_amdgcn_rcpf(1.0f + t);
}
__device__ __forceinline__ float ftanh(float x){
  float t = __builtin_amdgcn_exp2f(2.88539008f * x);   // e^{2x}
  return 1.0f - 2.0f * __builtin_amdgcn_rcpf(1.0f + t);
}
__device__ __forceinline__ int pack2(float a, float b){
  return (int)(unsigned short)f2bf(a) | ((int)(unsigned short)f2bf(b) << 16);
}
// k-offset within a K=32 chunk for input-fragment element j, lane-half h=(lane>>4).
// flag=1: contiguous (k = 8h+j). flag=0: split halves (k = 4h+j | 16+4h+(j-4)).
__device__ __forceinline__ int koff(int flag, int h, int j){
  return flag ? (8*h + j) : (j < 4 ? 4*h + j : 16 + 4*h + (j-4));
}
// Assemble an A-fragment (8 bf16) from a row of 16-bit LDS at colbase.
__device__ __forceinline__ bf16x8 loadA(const short* p, int colbase, int h, int flag){
  if (flag){
    return *(const bf16x8*)(p + colbase + 8*h);
  } else {
    short4 lo = *(const short4*)(p + colbase + 4*h);
    short4 hi = *(const short4*)(p + colbase + 16 + 4*h);
    bf16x8 r;
    r[0]=lo.x; r[1]=lo.y; r[2]=lo.z; r[3]=lo.w;
    r[4]=hi.x; r[5]=hi.y; r[6]=hi.z; r[7]=hi.w;
    return r;
  }
}

// ---------------- probe: decide MFMA input-fragment layout ------------------
__device__ __noinline__ void spin_units(int n){
  float x = 1.5f;
  for (int i=0; i<n*300; i++) x = __builtin_amdgcn_rcpf(x + 1.0f);
  asm volatile("" :: "v"(x));
}
__global__ __launch_bounds__(64) void probe_kernel(char* ws){
  int l = threadIdx.x;
  float dref[4]; int n = l & 15;
  #pragma unroll
  for (int r=0;r<4;r++){
    int m = 4*(l>>4) + r; float s = 0.f;
    for (int k=0;k<32;k++)
      s += (0.25f*(float)((m*7+k*3)%5-2)) * (0.125f*(float)((k*5+n*11)%7-3));
    dref[r] = s;
  }
  f32x4 zero = {0.f,0.f,0.f,0.f};
  int bad[2];
  #pragma unroll
  for (int cand=0; cand<2; cand++){          // 0=split, 1=contiguous
    bf16x8 a, b;
    #pragma unroll
    for (int j=0;j<8;j++){
      int k = koff(cand, l>>4, j);
      a[j] = f2bf(0.25f*(float)(((l&15)*7+k*3)%5-2));
      b[j] = f2bf(0.125f*(float)((k*5+(l&15)*11)%7-3));
    }
    f32x4 d = __builtin_amdgcn_mfma_f32_16x16x32_bf16(a,b,zero,0,0,0);
    int bb = 0;
    #pragma unroll
    for (int r=0;r<4;r++) bb |= (fabsf(d[r]-dref[r]) > 1e-4f) ? 1 : 0;
    bad[cand] = bb;
  }
  unsigned long long B2 = __ballot(bad[1]);
  unsigned long long B1 = __ballot(bad[0]);
  if (l == 0) *(int*)(ws + FLAG_OFF) = (B2 == 0ULL) ? 1 : 0;
  if (B2) spin_units(10);
  if (B1) spin_units(30);
}

// ---------------- prep: pack Wh,Wi -> per-wave streamed B-frags -------------
// WF[e], e = ((dir*16+ww)*48 + f)*64 + lane, f = cs*4+G; elem j:
//   cs<4: Wi[cs*32 + koff][n], cs>=4: Wh[(cs-4)*32 + koff][n]
//   n = G*256 + ww*16 + (lane&15)
__global__ __launch_bounds__(256) void prep_kernel(const float* Wh_f, const float* Wh_b,
    const float* Wi_f, const float* Wi_b, char* ws){
  const int flag = *(const int*)(ws + FLAG_OFF);
  int e = blockIdx.x*256 + threadIdx.x;     // 98304 total
  int lane = e&63;
  int q = e>>6;                              // (dir*16+ww)*48 + f
  int f = q % 48, dw = q / 48;
  int ww = dw & 15, dir = dw >> 4;
  int cs = f>>2, G = f&3;
  const float* W; int kb;
  if (cs < 4){ W = dir ? Wi_b : Wi_f; kb = cs*32; }
  else       { W = dir ? Wh_b : Wh_f; kb = (cs-4)*32; }
  int nn = G*256 + ww*16 + (lane&15);
  int h = lane>>4;
  int kj[8];
  #pragma unroll
  for (int j=0;j<8;j++) kj[j] = kb + koff(flag, h, j);
  int4 pv;
  pv.x = pack2(W[kj[0]*1024+nn], W[kj[1]*1024+nn]);
  pv.y = pack2(W[kj[2]*1024+nn], W[kj[3]*1024+nn]);
  pv.z = pack2(W[kj[4]*1024+nn], W[kj[5]*1024+nn]);
  pv.w = pack2(W[kj[6]*1024+nn], W[kj[7]*1024+nn]);
  ((int4*)(ws + WF_OFF))[e] = pv;
}

// ---------------- embed: x as A-fragments: XF[t][blk][ks][lane] 16B ---------
__global__ __launch_bounds__(256) void embed_kernel(const int* tokens, const float* emb,
    char* ws){
  const int flag = *(const int*)(ws + FLAG_OFF);
  int e = blockIdx.x;               // 8192 = t*16 + blk
  int t = e >> 4, blk = e & 15;
  int tid = threadIdx.x;
  int ks = tid >> 6, lane = tid & 63;
  int h = lane >> 4, m = lane & 15;
  int b = blk*16 + m;
  int tok = tokens[b*S_LEN + t];
  const float* er = emb + (size_t)tok*128 + ks*32;
  float4 v0, v1;
  if (flag){
    v0 = *(const float4*)(er + 8*h);
    v1 = *(const float4*)(er + 8*h + 4);
  } else {
    v0 = *(const float4*)(er + 4*h);
    v1 = *(const float4*)(er + 16 + 4*h);
  }
  int4 pv;
  pv.x = pack2(v0.x,v0.y); pv.y = pack2(v0.z,v0.w);
  pv.z = pack2(v1.x,v1.y); pv.w = pack2(v1.z,v1.w);
  ((int4*)(ws + XF_OFF))[((size_t)e*4 + ks)*64 + lane] = pv;
}

// ---------------- rnn: 32 blocks x 1024 thr, streamed weights ---------------
__device__ __forceinline__ void lstm_step(
    int t, int dir, int blk, int l, int flag, int hcol,
    const int4* xf4, const int4* wfw,
    int4 (&bq)[12], int4 (&xq)[4],
    const float (&bias)[4],
    const short* hRead, short* hWrite,
    float (&c)[4])
{
  const int hh = l>>4;
  const short* hR = hRead + (l&15)*264;
  f32x4 acc[4];
  #pragma unroll
  for (int G=0; G<4; G++){
    f32x4 v = {bias[G],bias[G],bias[G],bias[G]}; acc[G] = v;
  }
  // 2-deep LDS prefetch of h A-frags (chunks 4,5 first)
  bf16x8 afA = loadA(hR, 0,  hh, flag);
  bf16x8 afB = loadA(hR, 32, hh, flag);

  #pragma unroll
  for (int cs=0; cs<12; cs++){
    bf16x8 af;
    if (cs < 4)       af = __builtin_bit_cast(bf16x8, xq[cs]);
    else if (cs & 1){ af = afB; if (cs < 10) afB = loadA(hR, (cs-2)*32, hh, flag); }
    else            { af = afA; if (cs < 10) afA = loadA(hR, (cs-2)*32, hh, flag); }
    #pragma unroll
    for (int G=0; G<4; G++){
      const int f = cs*4 + G;
      acc[G] = __builtin_amdgcn_mfma_f32_16x16x32_bf16(af,
                 __builtin_bit_cast(bf16x8, bq[f%12]), acc[G], 0,0,0);
    }
    // refill slots with f+12 (mod 48): lead = 12 fragments, wraps across steps
    #pragma unroll
    for (int G=0; G<4; G++){
      const int f = cs*4 + G;
      bq[f%12] = wfw[(size_t)((f+12)%48)*64 + l];
    }
    if (cs == 3){
      // xq consumed; reload for t+1 (lands during chunks 4..11 + gates)
      int tn = (t+1 < S_LEN) ? t+1 : t;
      int tt = dir ? (S_LEN-1-tn) : tn;
      size_t xi = (((size_t)tt*16 + blk)*4)*64 + l;
      xq[0] = xf4[xi];     xq[1] = xf4[xi+64];
      xq[2] = xf4[xi+128]; xq[3] = xf4[xi+192];
    }
  }
  // gates (i,f,g,o = acc[0..3]); batch row m = 4*(l>>4)+r, hidden col hcol
  #pragma unroll
  for (int r=0; r<4; r++){
    float iv = acc[0][r];
    float fv = acc[1][r];
    float gv = acc[2][r];
    float ov = acc[3][r];
    float cc = fsig(fv)*c[r] + fsig(iv)*ftanh(gv);
    c[r] = cc;
    float hhv = fsig(ov)*ftanh(cc);
    hWrite[(4*(l>>4)+r)*264 + hcol] = f2bf(hhv);
  }
  __syncthreads();
}

__global__
__attribute__((amdgpu_flat_work_group_size(1024, 1024), amdgpu_waves_per_eu(4, 4)))
void rnn_kernel(const float* b_f, const float* b_b, char* ws){
  const int flag = *(const int*)(ws + FLAG_OFF);
  int bid = blockIdx.x; int dir = bid>>4, blk = bid&15;
  int tid = threadIdx.x; int ww = tid>>6, l = tid&63;
  __shared__ short hbuf[2][16*264];
  for (int i=tid; i<16*264; i+=1024) hbuf[0][i] = 0;
  const int4* xf4 = (const int4*)(ws + XF_OFF);
  const int4* wfw = (const int4*)(ws + WF_OFF) + ((size_t)(dir*16 + ww)*48)*64;
  float bias[4];
  {
    const float* bh = dir ? b_b : b_f;
    #pragma unroll
    for (int G=0; G<4; G++) bias[G] = bh[G*256 + ww*16 + (l&15)];
  }
  const int hcol = ww*16 + (l&15);
  float c[4] = {0,0,0,0};
  int4 bq[12], xq[4];
  #pragma unroll
  for (int s=0; s<12; s++) bq[s] = wfw[(size_t)s*64 + l];
  {
    int tt0 = dir ? (S_LEN-1) : 0;
    size_t xi0 = (((size_t)tt0*16 + blk)*4)*64 + l;
    xq[0]=xf4[xi0];     xq[1]=xf4[xi0+64];
    xq[2]=xf4[xi0+128]; xq[3]=xf4[xi0+192];
  }
  __syncthreads();
  #pragma unroll 1
  for (int t=0; t<S_LEN; t+=2){
    lstm_step(t,   dir, blk, l, flag, hcol, xf4, wfw, bq, xq, bias, hbuf[0], hbuf[1], c);
    lstm_step(t+1, dir, blk, l, flag, hcol, xf4, wfw, bq, xq, bias, hbuf[1], hbuf[0], c);
  }
  float* feat = (float*)(ws + FEAT_OFF);
  #pragma unroll
  for (int r=0; r<4; r++)
    feat[((size_t)blk*16 + 4*(l>>4)+r)*512 + dir*256 + hcol] = c[r];
}

// ---------------- head: feat@Wd+bd ------------------------------------------
__global__ __launch_bounds__(256) void head_kernel(const float* Wd, const float* bd,
    const char* ws, float* out){
  __shared__ float wds[4096];
  int tid = threadIdx.x;
  for (int i=tid; i<4096; i+=256) wds[i] = Wd[i];
  __syncthreads();
  if (tid < 128){
    int row = blockIdx.x*16 + (tid>>3), col = tid&7;
    const float* fr = (const float*)(ws + FEAT_OFF) + (size_t)row*512;
    float s = bd[col];
    #pragma unroll 8
    for (int k=0;k<512;k++) s += fr[k]*wds[k*8+col];
    out[row*8+col] = s;
  }
}

extern "C" void kernel_launch(void* const* d_in, const int* in_sizes, int n_in,
                              void* d_out, int out_size, void* d_ws, size_t ws_size,
                              hipStream_t stream) {
  const int*   tokens = (const int*)d_in[0];
  const float* emb    = (const float*)d_in[1];
  const float* Wi_f   = (const float*)d_in[2];
  const float* Wh_f   = (const float*)d_in[3];
  const float* b_f    = (const float*)d_in[4];
  const float* Wi_b   = (const float*)d_in[5];
  const float* Wh_b   = (const float*)d_in[6];
  const float* b_b    = (const float*)d_in[7];
  const float* Wd     = (const float*)d_in[8];
  const float* bd     = (const float*)d_in[9];
  char* ws = (char*)d_ws;
  float* out = (float*)d_out;

  if (ws_size < WS_NEED) return;   // fail cleanly instead of faulting

  hipLaunchKernelGGL(probe_kernel, dim3(1),    dim3(64),   0, stream, ws);
  hipLaunchKernelGGL(prep_kernel,  dim3(384),  dim3(256),  0, stream, Wh_f, Wh_b, Wi_f, Wi_b, ws);
  hipLaunchKernelGGL(embed_kernel, dim3(8192), dim3(256),  0, stream, tokens, emb, ws);
  hipLaunchKernelGGL(rnn_kernel,   dim3(32),   dim3(1024), 0, stream, b_f, b_b, ws);
  hipLaunchKernelGGL(head_kernel,  dim3(16),   dim3(256),  0, stream, Wd, bd, ws, out);
}

// Round 12
// 5305.845 us; speedup vs baseline: 1.5600x; 1.5555x over previous
//
#include <hip/hip_runtime.h>
#include <hip/hip_bf16.h>

// BiLSTM classifier, MI355X — round 12 (= round-11 design, resubmitted after
// broker timeout; paper audit found no bugs).
// rnn: 32 blocks x 512 thr (the only shape the allocator demonstrably gives
// 128 VGPRs: r4 (512,2)->128; all 1024-thread variants pinned at 64 -> spill).
// Wave ww handles hc-tiles {ww, ww+8} serially per step; each tile's 48
// weight B-frags stream from L2 through a 12-slot rotating register buffer
// whose refill alternates tile0/tile1/next-step. Live set ~112 regs.

typedef __attribute__((ext_vector_type(8))) short bf16x8;
typedef __attribute__((ext_vector_type(4))) float f32x4;

#define S_LEN 512

// ws layout (bytes)
#define XF_OFF   0ULL
#define XF_SZ    (512ULL*16*4*64*16)           // 33,554,432
#define WF_OFF   (XF_OFF + XF_SZ)
#define WF_SZ    (2ULL*16*48*64*16)            // 1,572,864
#define FEAT_OFF (WF_OFF + WF_SZ)
#define FEAT_SZ  (256ULL*512*4)                // 524,288
#define FLAG_OFF (FEAT_OFF + FEAT_SZ)
#define WS_NEED  (FLAG_OFF + 16)

__device__ __forceinline__ short f2bf(float f){
  union { float f; unsigned u; } v; v.f = f;
  unsigned u = v.u;
  u += 0x7fffu + ((u >> 16) & 1u);   // RNE
  return (short)(u >> 16);
}
__device__ __forceinline__ float fsig(float x){
  float t = __builtin_amdgcn_exp2f(-1.44269504f * x);
  return __builtin_amdgcn_rcpf(1.0f + t);
}
__device__ __forceinline__ float ftanh(float x){
  float t = __builtin_amdgcn_exp2f(2.88539008f * x);   // e^{2x}
  return 1.0f - 2.0f * __builtin_amdgcn_rcpf(1.0f + t);
}
__device__ __forceinline__ int pack2(float a, float b){
  return (int)(unsigned short)f2bf(a) | ((int)(unsigned short)f2bf(b) << 16);
}
// k-offset within a K=32 chunk for input-fragment element j, lane-half h=(lane>>4).
// flag=1: contiguous (k = 8h+j). flag=0: split halves (k = 4h+j | 16+4h+(j-4)).
__device__ __forceinline__ int koff(int flag, int h, int j){
  return flag ? (8*h + j) : (j < 4 ? 4*h + j : 16 + 4*h + (j-4));
}
// Assemble an A-fragment (8 bf16) from a row of 16-bit LDS at colbase.
__device__ __forceinline__ bf16x8 loadA(const short* p, int colbase, int h, int flag){
  if (flag){
    return *(const bf16x8*)(p + colbase + 8*h);
  } else {
    short4 lo = *(const short4*)(p + colbase + 4*h);
    short4 hi = *(const short4*)(p + colbase + 16 + 4*h);
    bf16x8 r;
    r[0]=lo.x; r[1]=lo.y; r[2]=lo.z; r[3]=lo.w;
    r[4]=hi.x; r[5]=hi.y; r[6]=hi.z; r[7]=hi.w;
    return r;
  }
}

// ---------------- probe: decide MFMA input-fragment layout ------------------
__device__ __noinline__ void spin_units(int n){
  float x = 1.5f;
  for (int i=0; i<n*300; i++) x = __builtin_amdgcn_rcpf(x + 1.0f);
  asm volatile("" :: "v"(x));
}
__global__ __launch_bounds__(64) void probe_kernel(char* ws){
  int l = threadIdx.x;
  float dref[4]; int n = l & 15;
  #pragma unroll
  for (int r=0;r<4;r++){
    int m = 4*(l>>4) + r; float s = 0.f;
    for (int k=0;k<32;k++)
      s += (0.25f*(float)((m*7+k*3)%5-2)) * (0.125f*(float)((k*5+n*11)%7-3));
    dref[r] = s;
  }
  f32x4 zero = {0.f,0.f,0.f,0.f};
  int bad[2];
  #pragma unroll
  for (int cand=0; cand<2; cand++){          // 0=split, 1=contiguous
    bf16x8 a, b;
    #pragma unroll
    for (int j=0;j<8;j++){
      int k = koff(cand, l>>4, j);
      a[j] = f2bf(0.25f*(float)(((l&15)*7+k*3)%5-2));
      b[j] = f2bf(0.125f*(float)((k*5+(l&15)*11)%7-3));
    }
    f32x4 d = __builtin_amdgcn_mfma_f32_16x16x32_bf16(a,b,zero,0,0,0);
    int bb = 0;
    #pragma unroll
    for (int r=0;r<4;r++) bb |= (fabsf(d[r]-dref[r]) > 1e-4f) ? 1 : 0;
    bad[cand] = bb;
  }
  unsigned long long B2 = __ballot(bad[1]);
  unsigned long long B1 = __ballot(bad[0]);
  if (l == 0) *(int*)(ws + FLAG_OFF) = (B2 == 0ULL) ? 1 : 0;
  if (B2) spin_units(10);
  if (B1) spin_units(30);
}

// ---------------- prep: pack Wh,Wi -> per-tile streamed B-frags -------------
// WF[e], e = ((dir*16+w)*48 + f)*64 + lane, f = cs*4+G; elem j:
//   cs<4: Wi[cs*32 + koff][n], cs>=4: Wh[(cs-4)*32 + koff][n]
//   n = G*256 + w*16 + (lane&15)     (w = hc-tile index 0..15)
__global__ __launch_bounds__(256) void prep_kernel(const float* Wh_f, const float* Wh_b,
    const float* Wi_f, const float* Wi_b, char* ws){
  const int flag = *(const int*)(ws + FLAG_OFF);
  int e = blockIdx.x*256 + threadIdx.x;     // 98304 total
  int lane = e&63;
  int q = e>>6;                              // (dir*16+w)*48 + f
  int f = q % 48, dw = q / 48;
  int w = dw & 15, dir = dw >> 4;
  int cs = f>>2, G = f&3;
  const float* W; int kb;
  if (cs < 4){ W = dir ? Wi_b : Wi_f; kb = cs*32; }
  else       { W = dir ? Wh_b : Wh_f; kb = (cs-4)*32; }
  int nn = G*256 + w*16 + (lane&15);
  int h = lane>>4;
  int kj[8];
  #pragma unroll
  for (int j=0;j<8;j++) kj[j] = kb + koff(flag, h, j);
  int4 pv;
  pv.x = pack2(W[kj[0]*1024+nn], W[kj[1]*1024+nn]);
  pv.y = pack2(W[kj[2]*1024+nn], W[kj[3]*1024+nn]);
  pv.z = pack2(W[kj[4]*1024+nn], W[kj[5]*1024+nn]);
  pv.w = pack2(W[kj[6]*1024+nn], W[kj[7]*1024+nn]);
  ((int4*)(ws + WF_OFF))[e] = pv;
}

// ---------------- embed: x as A-fragments: XF[t][blk][ks][lane] 16B ---------
__global__ __launch_bounds__(256) void embed_kernel(const int* tokens, const float* emb,
    char* ws){
  const int flag = *(const int*)(ws + FLAG_OFF);
  int e = blockIdx.x;               // 8192 = t*16 + blk
  int t = e >> 4, blk = e & 15;
  int tid = threadIdx.x;
  int ks = tid >> 6, lane = tid & 63;
  int h = lane >> 4, m = lane & 15;
  int b = blk*16 + m;
  int tok = tokens[b*S_LEN + t];
  const float* er = emb + (size_t)tok*128 + ks*32;
  float4 v0, v1;
  if (flag){
    v0 = *(const float4*)(er + 8*h);
    v1 = *(const float4*)(er + 8*h + 4);
  } else {
    v0 = *(const float4*)(er + 4*h);
    v1 = *(const float4*)(er + 16 + 4*h);
  }
  int4 pv;
  pv.x = pack2(v0.x,v0.y); pv.y = pack2(v0.z,v0.w);
  pv.z = pack2(v1.x,v1.y); pv.w = pack2(v1.z,v1.w);
  ((int4*)(ws + XF_OFF))[((size_t)e*4 + ks)*64 + lane] = pv;
}

// ---------------- rnn: 32 blocks x 512 thr, 2 hc-tiles per wave -------------
__device__ __forceinline__ void lstm_step(
    int t, int dir, int blk, int l, int flag,
    const int4* xf4, const int4* wfw0, const int4* wfw1,
    int4 (&bq)[12], int4 (&xq)[4],
    const float (&bias)[2][4],
    const short* hRead, short* hWrite,
    float (&c)[2][4], int hcol0, int hcol1)
{
  const int hh = l>>4;
  const short* hR = hRead + (l&15)*264;
  #pragma unroll
  for (int p=0; p<2; p++){
    const int4* wsrc  = p ? wfw1 : wfw0;   // this tile's frags
    const int4* wnext = p ? wfw0 : wfw1;   // next in stream (other tile)
    f32x4 acc[4];
    #pragma unroll
    for (int G=0; G<4; G++){
      f32x4 v = {bias[p][G],bias[p][G],bias[p][G],bias[p][G]}; acc[G] = v;
    }
    // 2-deep LDS prefetch of h A-frags (chunks 4,5 first)
    bf16x8 afA = loadA(hR, 0,  hh, flag);
    bf16x8 afB = loadA(hR, 32, hh, flag);
    #pragma unroll
    for (int cs=0; cs<12; cs++){
      bf16x8 af;
      if (cs < 4)       af = __builtin_bit_cast(bf16x8, xq[cs]);
      else if (cs & 1){ af = afB; if (cs < 10) afB = loadA(hR, (cs-2)*32, hh, flag); }
      else            { af = afA; if (cs < 10) afA = loadA(hR, (cs-2)*32, hh, flag); }
      #pragma unroll
      for (int G=0; G<4; G++){
        const int f = cs*4 + G;
        acc[G] = __builtin_amdgcn_mfma_f32_16x16x32_bf16(af,
                   __builtin_bit_cast(bf16x8, bq[f%12]), acc[G], 0,0,0);
      }
      // refill with frag f+12 of the alternating stream (lead = 12 frags)
      #pragma unroll
      for (int G=0; G<4; G++){
        const int f = cs*4 + G;
        const int nf = f + 12;
        bq[f%12] = (nf < 48) ? wsrc[(size_t)nf*64 + l]
                             : wnext[(size_t)(nf-48)*64 + l];
      }
      if (p == 1 && cs == 3){
        // xq fully consumed; reload for t+1 (lands during chunks 4..11+gates)
        int tn = (t+1 < S_LEN) ? t+1 : t;
        int tt = dir ? (S_LEN-1-tn) : tn;
        size_t xi = (((size_t)tt*16 + blk)*4)*64 + l;
        xq[0] = xf4[xi];     xq[1] = xf4[xi+64];
        xq[2] = xf4[xi+128]; xq[3] = xf4[xi+192];
      }
    }
    // gates (i,f,g,o = acc[0..3]); batch row m=4*(l>>4)+r, hidden col hcol_p
    const int hc = p ? hcol1 : hcol0;
    #pragma unroll
    for (int r=0; r<4; r++){
      float iv = acc[0][r];
      float fv = acc[1][r];
      float gv = acc[2][r];
      float ov = acc[3][r];
      float cc = fsig(fv)*c[p][r] + fsig(iv)*ftanh(gv);
      c[p][r] = cc;
      float hhv = fsig(ov)*ftanh(cc);
      hWrite[(4*(l>>4)+r)*264 + hc] = f2bf(hhv);
    }
  }
  __syncthreads();
}

__global__ __launch_bounds__(512, 2) void rnn_kernel(const float* b_f, const float* b_b,
    char* ws){
  const int flag = *(const int*)(ws + FLAG_OFF);
  int bid = blockIdx.x; int dir = bid>>4, blk = bid&15;
  int tid = threadIdx.x; int ww = tid>>6, l = tid&63;
  __shared__ short hbuf[2][16*264];
  for (int i=tid; i<16*264; i+=512) hbuf[0][i] = 0;
  const int4* xf4  = (const int4*)(ws + XF_OFF);
  const int4* wfw0 = (const int4*)(ws + WF_OFF) + ((size_t)(dir*16 + ww    )*48)*64;
  const int4* wfw1 = (const int4*)(ws + WF_OFF) + ((size_t)(dir*16 + ww + 8)*48)*64;
  float bias[2][4];
  {
    const float* bh = dir ? b_b : b_f;
    #pragma unroll
    for (int p=0; p<2; p++)
      #pragma unroll
      for (int G=0; G<4; G++) bias[p][G] = bh[G*256 + (ww + 8*p)*16 + (l&15)];
  }
  const int hcol0 = ww*16 + (l&15);
  const int hcol1 = (ww+8)*16 + (l&15);
  float c[2][4] = {{0,0,0,0},{0,0,0,0}};
  int4 bq[12], xq[4];
  #pragma unroll
  for (int s=0; s<12; s++) bq[s] = wfw0[(size_t)s*64 + l];
  {
    int tt0 = dir ? (S_LEN-1) : 0;
    size_t xi0 = (((size_t)tt0*16 + blk)*4)*64 + l;
    xq[0]=xf4[xi0];     xq[1]=xf4[xi0+64];
    xq[2]=xf4[xi0+128]; xq[3]=xf4[xi0+192];
  }
  __syncthreads();
  #pragma unroll 1
  for (int t=0; t<S_LEN; t+=2){
    lstm_step(t,   dir, blk, l, flag, xf4, wfw0, wfw1, bq, xq, bias,
              hbuf[0], hbuf[1], c, hcol0, hcol1);
    lstm_step(t+1, dir, blk, l, flag, xf4, wfw0, wfw1, bq, xq, bias,
              hbuf[1], hbuf[0], c, hcol0, hcol1);
  }
  float* feat = (float*)(ws + FEAT_OFF);
  #pragma unroll
  for (int p=0; p<2; p++)
    #pragma unroll
    for (int r=0; r<4; r++)
      feat[((size_t)blk*16 + 4*(l>>4)+r)*512 + dir*256 + (p ? hcol1 : hcol0)] = c[p][r];
}

// ---------------- head: feat@Wd+bd ------------------------------------------
__global__ __launch_bounds__(256) void head_kernel(const float* Wd, const float* bd,
    const char* ws, float* out){
  __shared__ float wds[4096];
  int tid = threadIdx.x;
  for (int i=tid; i<4096; i+=256) wds[i] = Wd[i];
  __syncthreads();
  if (tid < 128){
    int row = blockIdx.x*16 + (tid>>3), col = tid&7;
    const float* fr = (const float*)(ws + FEAT_OFF) + (size_t)row*512;
    float s = bd[col];
    #pragma unroll 8
    for (int k=0;k<512;k++) s += fr[k]*wds[k*8+col];
    out[row*8+col] = s;
  }
}

extern "C" void kernel_launch(void* const* d_in, const int* in_sizes, int n_in,
                              void* d_out, int out_size, void* d_ws, size_t ws_size,
                              hipStream_t stream) {
  const int*   tokens = (const int*)d_in[0];
  const float* emb    = (const float*)d_in[1];
  const float* Wi_f   = (const float*)d_in[2];
  const float* Wh_f   = (const float*)d_in[3];
  const float* b_f    = (const float*)d_in[4];
  const float* Wi_b   = (const float*)d_in[5];
  const float* Wh_b   = (const float*)d_in[6];
  const float* b_b    = (const float*)d_in[7];
  const float* Wd     = (const float*)d_in[8];
  const float* bd     = (const float*)d_in[9];
  char* ws = (char*)d_ws;
  float* out = (float*)d_out;

  if (ws_size < WS_NEED) return;   // fail cleanly instead of faulting

  hipLaunchKernelGGL(probe_kernel, dim3(1),    dim3(64),  0, stream, ws);
  hipLaunchKernelGGL(prep_kernel,  dim3(384),  dim3(256), 0, stream, Wh_f, Wh_b, Wi_f, Wi_b, ws);
  hipLaunchKernelGGL(embed_kernel, dim3(8192), dim3(256), 0, stream, tokens, emb, ws);
  hipLaunchKernelGGL(rnn_kernel,   dim3(32),   dim3(512), 0, stream, b_f, b_b, ws);
  hipLaunchKernelGGL(head_kernel,  dim3(16),   dim3(256), 0, stream, Wd, bd, ws, out);
}